// Round 5
// baseline (699.984 us; speedup 1.0000x reference)
//
#include <hip/hip_runtime.h>

// N=500000, D=64, K=512 (fp32 in/out).
// out rows: [0,K)=xw_sum, [K,2K)=w_sum, row 2K = inertia broadcast to 64 cols.

#define D_DIM 64
#define K_CLUS 512
#define SEG 16
#define SEG_SHIFT 4

typedef __attribute__((ext_vector_type(8))) short short8;
typedef __attribute__((ext_vector_type(4))) float f32x4;

__device__ inline float dot4sq(float4 a) {
    return a.x * a.x + a.y * a.y + a.z * a.z + a.w * a.w;
}
__device__ inline unsigned short bfb(float f) {   // fp32 -> bf16 bits, RNE
    unsigned int u = __float_as_uint(f);
    return (unsigned short)((u + 0x7FFFu + ((u >> 16) & 1u)) >> 16);
}
__device__ inline short8 pack8(float4 a, float4 b) {
    short8 r;
    r[0] = (short)bfb(a.x); r[1] = (short)bfb(a.y);
    r[2] = (short)bfb(a.z); r[3] = (short)bfb(a.w);
    r[4] = (short)bfb(b.x); r[5] = (short)bfb(b.y);
    r[6] = (short)bfb(b.z); r[7] = (short)bfb(b.w);
    return r;
}
__device__ inline float4 shfl_xor4(float4 v, int m) {
    float4 r;
    r.x = __shfl_xor(v.x, m); r.y = __shfl_xor(v.y, m);
    r.z = __shfl_xor(v.z, m); r.w = __shfl_xor(v.w, m);
    return r;
}

// ---------------- Kernel 1: half-norms + bf16 pack of centroids ----------------
__global__ void cc_kernel(const float* __restrict__ C, float* __restrict__ CChalf,
                          unsigned short* __restrict__ Cb, int k_total) {
    int k = blockIdx.x * blockDim.x + threadIdx.x;
    if (k >= k_total) return;
    const float4* cp = (const float4*)(C + (size_t)k * D_DIM);
    unsigned short* ob = Cb + (size_t)k * D_DIM;
    float s = 0.f;
#pragma unroll
    for (int i = 0; i < 16; ++i) {
        float4 c = cp[i];
        s += dot4sq(c);
        ob[4 * i + 0] = bfb(c.x); ob[4 * i + 1] = bfb(c.y);
        ob[4 * i + 2] = bfb(c.z); ob[4 * i + 3] = bfb(c.w);
    }
    CChalf[k] = 0.5f * s;
}

// ---------------- Kernel 2: persistent MFMA assignment ----------------
// argmin_k ||x-c_k||^2 == argmax_k (x.c_k - 0.5||c_k||^2).
// 512 thr / 8 waves; grid = 512 persistent blocks (2/CU, LDS-limited).
// C (bf16) staged once per block in LDS (XOR-swizzled); grid-stride over
// 128-row tiles; 1-deep register prefetch of B-frags; X prefetch for next tile.
__global__ __launch_bounds__(512) void assign_mfma(
        const float* __restrict__ X, const unsigned short* __restrict__ Cb,
        const float* __restrict__ CChalf, int* __restrict__ y,
        int* __restrict__ rank, int* __restrict__ count,
        float* __restrict__ inertia_ws, int n, int ntiles) {
    __shared__ __align__(16) char c_lds[K_CLUS * D_DIM * 2];   // 64 KB
    __shared__ float cchalf_lds[K_CLUS];
    __shared__ float wsum8[8];
    int tid = threadIdx.x;

    // stage C_bf16 -> LDS, phys(row,b) = row*128 + (b ^ ((row&7)<<4))
    const uint4* Cb4 = (const uint4*)Cb;
#pragma unroll
    for (int it = 0; it < 8; ++it) {
        int c = tid + it * 512;               // 16B chunk id, 8 per row
        uint4 v = Cb4[c];
        int row = c >> 3;
        int b = (c & 7) << 4;
        *(uint4*)(c_lds + (row << 7) + (b ^ ((row & 7) << 4))) = v;
    }
    cchalf_lds[tid] = CChalf[tid];            // 512 threads == K_CLUS
    __syncthreads();

    int lane = tid & 63, wid = tid >> 6;
    int c15 = lane & 15, g = lane >> 4;       // A row = c15, k-group = g
    int g16 = g << 4;
    const float4* X4 = (const float4*)X;

    float iner = 0.f;
    int tileIdx = blockIdx.x;

    // prologue: X for first tile
    float4 f0, f1, f2, f3;
    {
        int lrow = min(tileIdx * 128 + wid * 16 + c15, n - 1);
        size_t xb = (size_t)lrow * 16;
        f0 = X4[xb + g * 2];     f1 = X4[xb + g * 2 + 1];
        f2 = X4[xb + 8 + g * 2]; f3 = X4[xb + 9 + g * 2];
    }

    while (tileIdx < ntiles) {
        int nextIdx = tileIdx + gridDim.x;
        int rowbase = tileIdx * 128;

        float xs = dot4sq(f0) + dot4sq(f1) + dot4sq(f2) + dot4sq(f3);
        xs += __shfl_xor(xs, 16);
        xs += __shfl_xor(xs, 32);             // each lane: ||x_row(c15)||^2
        short8 a0 = pack8(f0, f1), a1 = pack8(f2, f3);

        // prefetch next tile's X rows (block-uniform branch)
        if (nextIdx < ntiles) {
            int lrow = min(nextIdx * 128 + wid * 16 + c15, n - 1);
            size_t xb = (size_t)lrow * 16;
            f0 = X4[xb + g * 2];     f1 = X4[xb + g * 2 + 1];
            f2 = X4[xb + 8 + g * 2]; f3 = X4[xb + 9 + g * 2];
        }

        float best[4] = {-3.4e38f, -3.4e38f, -3.4e38f, -3.4e38f};
        int bestk[4] = {0, 0, 0, 0};

        // preload tile-0 B frags
        int col0 = c15;
        float cch = cchalf_lds[col0];
        const char* bp0 = c_lds + (col0 << 7);
        int swz0 = (col0 & 7) << 4;
        short8 b0 = *(const short8*)(bp0 + (g16 ^ swz0));
        short8 b1 = *(const short8*)(bp0 + ((g16 + 64) ^ swz0));

        for (int tile = 0; tile < 32; ++tile) {
            // 1-deep prefetch (wraps at 31 -> harmless reload of tile 0)
            int ncol = (((tile + 1) & 31) << 4) + c15;
            const char* nbp = c_lds + (ncol << 7);
            int nswz = (ncol & 7) << 4;
            short8 nb0 = *(const short8*)(nbp + (g16 ^ nswz));
            short8 nb1 = *(const short8*)(nbp + ((g16 + 64) ^ nswz));
            float ncch = cchalf_lds[ncol];

            // two independent accumulators (K halves) to break MFMA dep chain
            f32x4 accA = {-cch, -cch, -cch, -cch};
            f32x4 accB = {0.f, 0.f, 0.f, 0.f};
            accA = __builtin_amdgcn_mfma_f32_16x16x32_bf16(a0, b0, accA, 0, 0, 0);
            accB = __builtin_amdgcn_mfma_f32_16x16x32_bf16(a1, b1, accB, 0, 0, 0);

            int col = (tile << 4) + c15;      // D: col=lane&15, row=g*4+reg
#pragma unroll
            for (int r2 = 0; r2 < 4; ++r2) {
                float sc = accA[r2] + accB[r2];
                if (sc > best[r2]) { best[r2] = sc; bestk[r2] = col; }
            }
            b0 = nb0; b1 = nb1; cch = ncch;
        }

        // argmax across 16 cols (prefer lower k on ties)
#pragma unroll
        for (int off = 1; off < 16; off <<= 1) {
#pragma unroll
            for (int r2 = 0; r2 < 4; ++r2) {
                float so = __shfl_xor(best[r2], off);
                int ko = __shfl_xor(bestk[r2], off);
                if (so > best[r2] || (so == best[r2] && ko < bestk[r2])) {
                    best[r2] = so; bestk[r2] = ko;
                }
            }
        }
#pragma unroll
        for (int r2 = 0; r2 < 4; ++r2) {
            int r = (g << 2) + r2;             // row within wave
            float xxr = __shfl(xs, r);         // all lanes participate
            if (c15 == r2) {
                int grow = rowbase + (wid << 4) + r;
                if (grow < n) {
                    y[grow] = bestk[r2];
                    rank[grow] = atomicAdd(count + bestk[r2], 1);
                    iner += sqrtf(fmaxf(xxr - 2.f * best[r2], 0.f) * (1.0f / 64.0f));
                }
            }
        }
        tileIdx = nextIdx;
    }

    // block inertia reduce, one atomic per block
#pragma unroll
    for (int off = 1; off < 64; off <<= 1) iner += __shfl_xor(iner, off);
    if (lane == 0) wsum8[wid] = iner;
    __syncthreads();
    if (tid == 0) {
        float s = 0.f;
#pragma unroll
        for (int j = 0; j < 8; ++j) s += wsum8[j];
        atomicAdd(inertia_ws, s);
    }
}

// ---------------- Kernel 3: exclusive prefix sum over 512 counts ----------------
__global__ __launch_bounds__(K_CLUS) void prefix_kernel(
        const int* __restrict__ count, int* __restrict__ offset) {
    __shared__ int tmp[K_CLUS];
    int t = threadIdx.x;
    tmp[t] = count[t];
    __syncthreads();
    for (int s = 1; s < K_CLUS; s <<= 1) {
        int v = (t >= s) ? tmp[t - s] : 0;
        __syncthreads();
        tmp[t] += v;
        __syncthreads();
    }
    offset[t] = tmp[t] - count[t];
}

// ---------------- Kernel 4: scatter rows into cluster-sorted order ----------------
__global__ __launch_bounds__(256) void scatter_kernel(
        const int* __restrict__ y, const int* __restrict__ rank,
        const int* __restrict__ offset, int* __restrict__ sorted, int n) {
    int row = blockIdx.x * blockDim.x + threadIdx.x;
    if (row >= n) return;
    sorted[offset[y[row]] + rank[row]] = row;
}

// ---------------- Kernel 5: segmented per-cluster accumulation ----------------
__global__ __launch_bounds__(256) void cluster_accum_seg(
        const float* __restrict__ X, const float* __restrict__ W,
        const int* __restrict__ sorted, const int* __restrict__ offset,
        const int* __restrict__ count, float* __restrict__ out) {
    int bid = blockIdx.x;
    int k = bid >> SEG_SHIFT;
    int seg = bid & (SEG - 1);
    int cnt = count[k];
    int chunk = (cnt + SEG - 1) >> SEG_SHIFT;
    int lo = seg * chunk;
    int hi = min(cnt, lo + chunk);
    int start = offset[k];
    int lane = threadIdx.x & 63, w = threadIdx.x >> 6;
    int rsub = lane >> 4, col4 = lane & 15;
    const float4* X4 = (const float4*)X;
    const float4* W4 = (const float4*)W;

    float4 ax = {0.f, 0.f, 0.f, 0.f}, aw = {0.f, 0.f, 0.f, 0.f};
    for (int base = lo + w * 4; base < hi; base += 16) {
        int ii = base + rsub;
        if (ii < hi) {
            int row = sorted[start + ii];
            float4 xv = X4[(size_t)row * 16 + col4];
            float4 wv = W4[(size_t)row * 16 + col4];
            ax.x = fmaf(xv.x, wv.x, ax.x); ax.y = fmaf(xv.y, wv.y, ax.y);
            ax.z = fmaf(xv.z, wv.z, ax.z); ax.w = fmaf(xv.w, wv.w, ax.w);
            aw.x += wv.x; aw.y += wv.y; aw.z += wv.z; aw.w += wv.w;
        }
    }
    float4 t;
    t = shfl_xor4(ax, 16); ax.x += t.x; ax.y += t.y; ax.z += t.z; ax.w += t.w;
    t = shfl_xor4(ax, 32); ax.x += t.x; ax.y += t.y; ax.z += t.z; ax.w += t.w;
    t = shfl_xor4(aw, 16); aw.x += t.x; aw.y += t.y; aw.z += t.z; aw.w += t.w;
    t = shfl_xor4(aw, 32); aw.x += t.x; aw.y += t.y; aw.z += t.z; aw.w += t.w;

    __shared__ float4 sx4[4][16];
    __shared__ float4 sw4[4][16];
    if (lane < 16) { sx4[w][lane] = ax; sw4[w][lane] = aw; }
    __syncthreads();
    if (threadIdx.x < 16) {
        int c = threadIdx.x;
        float4 tx = {0.f, 0.f, 0.f, 0.f}, tw = {0.f, 0.f, 0.f, 0.f};
#pragma unroll
        for (int j = 0; j < 4; ++j) {
            float4 a = sx4[j][c], b = sw4[j][c];
            tx.x += a.x; tx.y += a.y; tx.z += a.z; tx.w += a.w;
            tw.x += b.x; tw.y += b.y; tw.z += b.z; tw.w += b.w;
        }
        float* xw = out + (size_t)k * D_DIM + c * 4;
        float* wp = out + (size_t)(K_CLUS + k) * D_DIM + c * 4;
        atomicAdd(xw + 0, tx.x); atomicAdd(xw + 1, tx.y);
        atomicAdd(xw + 2, tx.z); atomicAdd(xw + 3, tx.w);
        atomicAdd(wp + 0, tw.x); atomicAdd(wp + 1, tw.y);
        atomicAdd(wp + 2, tw.z); atomicAdd(wp + 3, tw.w);
    }
}

// ---------------- Kernel 6: broadcast inertia ----------------
__global__ void finalize_kernel(const float* __restrict__ inertia_ws, float* __restrict__ out) {
    out[(size_t)(2 * K_CLUS) * D_DIM + threadIdx.x] = *inertia_ws;
}

// ---------------- Fallback path (ws too small) ----------------
__global__ __launch_bounds__(256) void assign_scalar(
        const float* __restrict__ X, const float* __restrict__ C,
        const float* __restrict__ CChalf, int* __restrict__ y,
        int* __restrict__ count, float* __restrict__ inertia_ws, int n) {
    int row = blockIdx.x * blockDim.x + threadIdx.x;
    float mind = 0.f;
    if (row < n) {
        float4 x[16];
        const float4* xp = (const float4*)(X + (size_t)row * D_DIM);
#pragma unroll
        for (int i = 0; i < 16; ++i) x[i] = xp[i];
        float xx = 0.f;
#pragma unroll
        for (int i = 0; i < 16; ++i) xx += dot4sq(x[i]);
        float best = -3.4e38f;
        int bestk = 0;
        for (int k = 0; k < K_CLUS; ++k) {
            const float4* cp = (const float4*)(C + (size_t)k * D_DIM);
            float s0 = 0.f;
#pragma unroll
            for (int i = 0; i < 16; ++i) {
                float4 c = cp[i];
                s0 += x[i].x * c.x + x[i].y * c.y + x[i].z * c.z + x[i].w * c.w;
            }
            float sc = s0 - CChalf[k];
            if (sc > best) { best = sc; bestk = k; }
        }
        y[row] = bestk;
        atomicAdd(&count[bestk], 1);
        mind = sqrtf(fmaxf(xx - 2.f * best, 0.f) * (1.0f / 64.0f));
    }
    float s = mind;
#pragma unroll
    for (int off = 32; off > 0; off >>= 1) s += __shfl_xor(s, off);
    __shared__ float wsum[4];
    int w = threadIdx.x >> 6;
    if ((threadIdx.x & 63) == 0) wsum[w] = s;
    __syncthreads();
    if (threadIdx.x == 0)
        atomicAdd(inertia_ws, wsum[0] + wsum[1] + wsum[2] + wsum[3]);
}

__global__ __launch_bounds__(256) void accum_atomic_kernel(
        const float* __restrict__ X, const float* __restrict__ W,
        const int* __restrict__ y, float* __restrict__ out, int n) {
    int row = blockIdx.x * blockDim.x + threadIdx.x;
    if (row >= n) return;
    int k = y[row];
    const float4* xp = (const float4*)(X + (size_t)row * D_DIM);
    const float4* wp = (const float4*)(W + (size_t)row * D_DIM);
    float* xw = out + (size_t)k * D_DIM;
    float* wsv = out + (size_t)(K_CLUS + k) * D_DIM;
#pragma unroll
    for (int i = 0; i < 16; ++i) {
        float4 x = xp[i];
        float4 wq = wp[i];
        atomicAdd(xw + 4 * i + 0, x.x * wq.x);
        atomicAdd(xw + 4 * i + 1, x.y * wq.y);
        atomicAdd(xw + 4 * i + 2, x.z * wq.z);
        atomicAdd(xw + 4 * i + 3, x.w * wq.w);
        atomicAdd(wsv + 4 * i + 0, wq.x);
        atomicAdd(wsv + 4 * i + 1, wq.y);
        atomicAdd(wsv + 4 * i + 2, wq.z);
        atomicAdd(wsv + 4 * i + 3, wq.w);
    }
}

extern "C" void kernel_launch(void* const* d_in, const int* in_sizes, int n_in,
                              void* d_out, int out_size, void* d_ws, size_t ws_size,
                              hipStream_t stream) {
    const float* X = (const float*)d_in[0];
    const float* C = (const float*)d_in[1];
    const float* W = (const float*)d_in[2];
    float* out = (float*)d_out;
    int n = in_sizes[0] / D_DIM;        // 500000
    int k_total = in_sizes[1] / D_DIM;  // 512

    char* ws = (char*)d_ws;
    int*            count   = (int*)ws;                      // 2 KB
    float*          inertia = (float*)(ws + 2048);
    float*          cchalf  = (float*)(ws + 2560);           // 2 KB
    int*            offset  = (int*)(ws + 8192);             // 2 KB
    unsigned short* Cb      = (unsigned short*)(ws + 12288); // 64 KB bf16 C
    int*            yv      = (int*)(ws + 81920);
    int*            rank    = (int*)(ws + 81920 + (size_t)n * 4);
    int*            sorted  = (int*)(ws + 81920 + (size_t)n * 8);
    size_t needed = 81920 + (size_t)n * 12;

    int nblk = (n + 255) / 256;

    hipMemsetAsync(ws, 0, 4096, stream);                       // count + inertia
    hipMemsetAsync(d_out, 0, (size_t)out_size * sizeof(float), stream);
    cc_kernel<<<(k_total + 255) / 256, 256, 0, stream>>>(C, cchalf, Cb, k_total);

    if (ws_size >= needed) {
        int ntiles = (n + 127) / 128;
        int agrid = ntiles < 512 ? ntiles : 512;   // 2 blocks/CU, persistent
        assign_mfma<<<agrid, 512, 0, stream>>>(X, Cb, cchalf, yv, rank, count, inertia, n, ntiles);
        prefix_kernel<<<1, K_CLUS, 0, stream>>>(count, offset);
        scatter_kernel<<<nblk, 256, 0, stream>>>(yv, rank, offset, sorted, n);
        cluster_accum_seg<<<k_total * SEG, 256, 0, stream>>>(X, W, sorted, offset, count, out);
        finalize_kernel<<<1, D_DIM, 0, stream>>>(inertia, out);
    } else {
        assign_scalar<<<nblk, 256, 0, stream>>>(X, C, cchalf, yv, count, inertia, n);
        accum_atomic_kernel<<<nblk, 256, 0, stream>>>(X, W, yv, out, n);
        finalize_kernel<<<1, D_DIM, 0, stream>>>(inertia, out);
    }
}

// Round 6
// 386.597 us; speedup vs baseline: 1.8106x; 1.8106x over previous
//
#include <hip/hip_runtime.h>

// N=500000, D=64, K=512 (fp32 in/out).
// out rows: [0,K)=xw_sum, [K,2K)=w_sum, row 2K = inertia broadcast to 64 cols.

#define D_DIM 64
#define K_CLUS 512
#define SEG 16
#define SEG_SHIFT 4
#define RPT 64            // X rows per tile in assign

typedef __attribute__((ext_vector_type(8))) short short8;
typedef __attribute__((ext_vector_type(4))) float f32x4;

__device__ inline float dot4sq(float4 a) {
    return a.x * a.x + a.y * a.y + a.z * a.z + a.w * a.w;
}
__device__ inline unsigned short bfb(float f) {   // fp32 -> bf16 bits, RNE
    unsigned int u = __float_as_uint(f);
    return (unsigned short)((u + 0x7FFFu + ((u >> 16) & 1u)) >> 16);
}
__device__ inline short8 pack8(float4 a, float4 b) {
    short8 r;
    r[0] = (short)bfb(a.x); r[1] = (short)bfb(a.y);
    r[2] = (short)bfb(a.z); r[3] = (short)bfb(a.w);
    r[4] = (short)bfb(b.x); r[5] = (short)bfb(b.y);
    r[6] = (short)bfb(b.z); r[7] = (short)bfb(b.w);
    return r;
}
__device__ inline float4 shfl_xor4(float4 v, int m) {
    float4 r;
    r.x = __shfl_xor(v.x, m); r.y = __shfl_xor(v.y, m);
    r.z = __shfl_xor(v.z, m); r.w = __shfl_xor(v.w, m);
    return r;
}

// ---------------- Kernel 1: half-norms + bf16 pack of centroids ----------------
__global__ void cc_kernel(const float* __restrict__ C, float* __restrict__ CChalf,
                          unsigned short* __restrict__ Cb, int k_total) {
    int k = blockIdx.x * blockDim.x + threadIdx.x;
    if (k >= k_total) return;
    const float4* cp = (const float4*)(C + (size_t)k * D_DIM);
    unsigned short* ob = Cb + (size_t)k * D_DIM;
    float s = 0.f;
#pragma unroll
    for (int i = 0; i < 16; ++i) {
        float4 c = cp[i];
        s += dot4sq(c);
        ob[4 * i + 0] = bfb(c.x); ob[4 * i + 1] = bfb(c.y);
        ob[4 * i + 2] = bfb(c.z); ob[4 * i + 3] = bfb(c.w);
    }
    CChalf[k] = 0.5f * s;
}

// ---------------- Kernel 2: MFMA assignment, C-in-registers ----------------
// argmin_k ||x-c||^2 == argmax_k (x.c - 0.5||c||^2).
// 8 waves/block; wave w owns clusters [w*64,(w+1)*64) as MFMA *A* fragments in
// registers. X tiles (64 rows, bf16, XOR-swizzled) staged to LDS, read as B
// fragments. D[cluster][xrow]: per lane acc r2 -> cluster g*4+r2, col c15=xrow.
// Per-row argmin: 3 in-reg compares + 2 shfl-max on packed keys; cross-wave
// merge via LDS key table.
__global__ __launch_bounds__(512, 4) void assign_mfma(
        const float* __restrict__ X, const unsigned short* __restrict__ Cb,
        const float* __restrict__ CChalf, int* __restrict__ y,
        int* __restrict__ rank, int* __restrict__ count,
        float* __restrict__ inertia_ws, int n, int ntiles) {
    __shared__ __align__(16) char xb_lds[RPT * 128];        // 8 KB bf16, swizzled
    __shared__ __align__(16) unsigned int partial[RPT][8];  // 2 KB keys
    __shared__ float xs_lds[2][RPT];                        // ||x||^2, dbuf

    int tid = threadIdx.x;
    int lane = tid & 63, wid = tid >> 6;
    int c15 = lane & 15, g = lane >> 4;
    int wbase = wid * 64;

    // ---- one-time: wave's 64 clusters -> registers (A-frags) + cch ----
    short8 cf0[4], cf1[4];
    float cch[16];
#pragma unroll
    for (int ct = 0; ct < 4; ++ct) {
        const char* cp = (const char*)(Cb + (size_t)(wbase + ct * 16 + c15) * D_DIM);
        cf0[ct] = *(const short8*)(cp + (g << 4));          // k = 8g..8g+7
        cf1[ct] = *(const short8*)(cp + 64 + (g << 4));     // k = 32+8g..
#pragma unroll
        for (int r2 = 0; r2 < 4; ++r2)
            cch[ct * 4 + r2] = CChalf[wbase + ct * 16 + (g << 2) + r2];
    }

    // stage mapping: thread -> one 16B bf16 chunk of the 8KB tile
    int srow = tid >> 3;             // 0..63
    int sb = (tid & 7) << 4;         // bf16 byte offset 0..112
    int sf = (tid & 7) << 3;         // fp32 elem offset 0..56
    unsigned swz = ((unsigned)(srow & 7)) << 4;

    const float4* X4f;
    float4 s0 = {0,0,0,0}, s1 = {0,0,0,0};
    int tile = blockIdx.x;
    if (tile < ntiles) {
        int grow = min(tile * RPT + srow, n - 1);
        X4f = (const float4*)(X + (size_t)grow * D_DIM + sf);
        s0 = X4f[0]; s1 = X4f[1];
    }
    float iner = 0.f;
    int it = 0;

    for (; tile < ntiles; tile += gridDim.x, ++it) {
        int par = it & 1;
        // ---- stage tile -> LDS (swizzled) + ||x||^2 partials ----
        *(short8*)(xb_lds + (srow << 7) + (sb ^ swz)) = pack8(s0, s1);
        float ps = dot4sq(s0) + dot4sq(s1);
        ps += __shfl_xor(ps, 1); ps += __shfl_xor(ps, 2); ps += __shfl_xor(ps, 4);
        if ((tid & 7) == 0) xs_lds[par][srow] = ps;
        __syncthreads();                                   // stage visible

        // issue next tile's loads (latency hides under sweep)
        int ntile = tile + gridDim.x;
        if (ntile < ntiles) {
            int grow = min(ntile * RPT + srow, n - 1);
            const float4* xp = (const float4*)(X + (size_t)grow * D_DIM + sf);
            s0 = xp[0]; s1 = xp[1];
        }

        // ---- sweep: 4 row-subtiles x wave's 64 clusters ----
#pragma unroll
        for (int s = 0; s < 4; ++s) {
            int arow = s * 16 + c15;                       // x-row (B col)
            const char* ab = xb_lds + (arow << 7);
            unsigned asw = ((unsigned)(c15 & 7)) << 4;
            short8 xa = *(const short8*)(ab + ((g << 4) ^ asw));
            short8 xbv = *(const short8*)(ab + ((64 + (g << 4)) ^ asw));

            float best = -3.4e38f;
            int bpos = 0;
#pragma unroll
            for (int ct = 0; ct < 4; ++ct) {
                f32x4 accA = {0.f, 0.f, 0.f, 0.f};
                f32x4 accB = {0.f, 0.f, 0.f, 0.f};
                accA = __builtin_amdgcn_mfma_f32_16x16x32_bf16(cf0[ct], xa, accA, 0, 0, 0);
                accB = __builtin_amdgcn_mfma_f32_16x16x32_bf16(cf1[ct], xbv, accB, 0, 0, 0);
#pragma unroll
                for (int r2 = 0; r2 < 4; ++r2) {
                    float sc = (accA[r2] + accB[r2]) - cch[ct * 4 + r2];
                    if (sc > best) { best = sc; bpos = ct * 4 + r2; }  // low k first
                }
            }
            // pack (score, k) into monotone key; reduce over g (lanes ^16,^32)
            int kg = wbase + ((bpos >> 2) << 4) + (g << 2) + (bpos & 3);
            unsigned u = __float_as_uint(best);
            unsigned mono = u ^ ((u & 0x80000000u) ? 0xFFFFFFFFu : 0x80000000u);
            unsigned key = (mono & 0xFFFFFE00u) | ((unsigned)kg ^ 0x1FFu);
            unsigned o = (unsigned)__shfl_xor((int)key, 16); key = key > o ? key : o;
            o = (unsigned)__shfl_xor((int)key, 32); key = key > o ? key : o;
            if (g == 0) partial[s * 16 + c15][wid] = key;
        }
        __syncthreads();                                   // partials visible

        // ---- merge: 64 threads, one row each ----
        if (tid < RPT) {
            int grow = tile * RPT + tid;
            if (grow < n) {
                const uint4* pp = (const uint4*)&partial[tid][0];
                uint4 p0 = pp[0], p1 = pp[1];
                unsigned key = p0.x;
                key = key > p0.y ? key : p0.y;
                key = key > p0.z ? key : p0.z;
                key = key > p0.w ? key : p0.w;
                key = key > p1.x ? key : p1.x;
                key = key > p1.y ? key : p1.y;
                key = key > p1.z ? key : p1.z;
                key = key > p1.w ? key : p1.w;
                int kg = (int)((key & 0x1FFu) ^ 0x1FFu);
                unsigned m2 = (key & 0xFFFFFE00u) | 0x100u;    // midpoint restore
                unsigned ub = (m2 & 0x80000000u) ? (m2 ^ 0x80000000u) : ~m2;
                float sbest = __uint_as_float(ub);
                float xx = xs_lds[par][tid];
                y[grow] = kg;
                rank[grow] = atomicAdd(count + kg, 1);
                iner += sqrtf(fmaxf(xx - 2.f * sbest, 0.f) * (1.0f / 64.0f));
            }
        }
    }

    // inertia: only wave 0 accumulated; butterfly + one atomic
#pragma unroll
    for (int off = 1; off < 64; off <<= 1) iner += __shfl_xor(iner, off);
    if (tid == 0) atomicAdd(inertia_ws, iner);
}

// ---------------- Kernel 3: exclusive prefix sum over 512 counts ----------------
__global__ __launch_bounds__(K_CLUS) void prefix_kernel(
        const int* __restrict__ count, int* __restrict__ offset) {
    __shared__ int tmp[K_CLUS];
    int t = threadIdx.x;
    tmp[t] = count[t];
    __syncthreads();
    for (int s = 1; s < K_CLUS; s <<= 1) {
        int v = (t >= s) ? tmp[t - s] : 0;
        __syncthreads();
        tmp[t] += v;
        __syncthreads();
    }
    offset[t] = tmp[t] - count[t];
}

// ---------------- Kernel 4: scatter rows into cluster-sorted order ----------------
__global__ __launch_bounds__(256) void scatter_kernel(
        const int* __restrict__ y, const int* __restrict__ rank,
        const int* __restrict__ offset, int* __restrict__ sorted, int n) {
    int row = blockIdx.x * blockDim.x + threadIdx.x;
    if (row >= n) return;
    sorted[offset[y[row]] + rank[row]] = row;
}

// ---------------- Kernel 5: segmented per-cluster accumulation ----------------
__global__ __launch_bounds__(256) void cluster_accum_seg(
        const float* __restrict__ X, const float* __restrict__ W,
        const int* __restrict__ sorted, const int* __restrict__ offset,
        const int* __restrict__ count, float* __restrict__ out) {
    int bid = blockIdx.x;
    int k = bid >> SEG_SHIFT;
    int seg = bid & (SEG - 1);
    int cnt = count[k];
    int chunk = (cnt + SEG - 1) >> SEG_SHIFT;
    int lo = seg * chunk;
    int hi = min(cnt, lo + chunk);
    int start = offset[k];
    int lane = threadIdx.x & 63, w = threadIdx.x >> 6;
    int rsub = lane >> 4, col4 = lane & 15;
    const float4* X4 = (const float4*)X;
    const float4* W4 = (const float4*)W;

    float4 ax = {0.f, 0.f, 0.f, 0.f}, aw = {0.f, 0.f, 0.f, 0.f};
    for (int base = lo + w * 4; base < hi; base += 16) {
        int ii = base + rsub;
        if (ii < hi) {
            int row = sorted[start + ii];
            float4 xv = X4[(size_t)row * 16 + col4];
            float4 wv = W4[(size_t)row * 16 + col4];
            ax.x = fmaf(xv.x, wv.x, ax.x); ax.y = fmaf(xv.y, wv.y, ax.y);
            ax.z = fmaf(xv.z, wv.z, ax.z); ax.w = fmaf(xv.w, wv.w, ax.w);
            aw.x += wv.x; aw.y += wv.y; aw.z += wv.z; aw.w += wv.w;
        }
    }
    float4 t;
    t = shfl_xor4(ax, 16); ax.x += t.x; ax.y += t.y; ax.z += t.z; ax.w += t.w;
    t = shfl_xor4(ax, 32); ax.x += t.x; ax.y += t.y; ax.z += t.z; ax.w += t.w;
    t = shfl_xor4(aw, 16); aw.x += t.x; aw.y += t.y; aw.z += t.z; aw.w += t.w;
    t = shfl_xor4(aw, 32); aw.x += t.x; aw.y += t.y; aw.z += t.z; aw.w += t.w;

    __shared__ float4 sx4[4][16];
    __shared__ float4 sw4[4][16];
    if (lane < 16) { sx4[w][lane] = ax; sw4[w][lane] = aw; }
    __syncthreads();
    if (threadIdx.x < 16) {
        int c = threadIdx.x;
        float4 tx = {0.f, 0.f, 0.f, 0.f}, tw = {0.f, 0.f, 0.f, 0.f};
#pragma unroll
        for (int j = 0; j < 4; ++j) {
            float4 a = sx4[j][c], b = sw4[j][c];
            tx.x += a.x; tx.y += a.y; tx.z += a.z; tx.w += a.w;
            tw.x += b.x; tw.y += b.y; tw.z += b.z; tw.w += b.w;
        }
        float* xw = out + (size_t)k * D_DIM + c * 4;
        float* wp = out + (size_t)(K_CLUS + k) * D_DIM + c * 4;
        atomicAdd(xw + 0, tx.x); atomicAdd(xw + 1, tx.y);
        atomicAdd(xw + 2, tx.z); atomicAdd(xw + 3, tx.w);
        atomicAdd(wp + 0, tw.x); atomicAdd(wp + 1, tw.y);
        atomicAdd(wp + 2, tw.z); atomicAdd(wp + 3, tw.w);
    }
}

// ---------------- Kernel 6: broadcast inertia ----------------
__global__ void finalize_kernel(const float* __restrict__ inertia_ws, float* __restrict__ out) {
    out[(size_t)(2 * K_CLUS) * D_DIM + threadIdx.x] = *inertia_ws;
}

// ---------------- Fallback path (ws too small) ----------------
__global__ __launch_bounds__(256) void assign_scalar(
        const float* __restrict__ X, const float* __restrict__ C,
        const float* __restrict__ CChalf, int* __restrict__ y,
        int* __restrict__ count, float* __restrict__ inertia_ws, int n) {
    int row = blockIdx.x * blockDim.x + threadIdx.x;
    float mind = 0.f;
    if (row < n) {
        float4 x[16];
        const float4* xp = (const float4*)(X + (size_t)row * D_DIM);
#pragma unroll
        for (int i = 0; i < 16; ++i) x[i] = xp[i];
        float xx = 0.f;
#pragma unroll
        for (int i = 0; i < 16; ++i) xx += dot4sq(x[i]);
        float best = -3.4e38f;
        int bestk = 0;
        for (int k = 0; k < K_CLUS; ++k) {
            const float4* cp = (const float4*)(C + (size_t)k * D_DIM);
            float s0 = 0.f;
#pragma unroll
            for (int i = 0; i < 16; ++i) {
                float4 c = cp[i];
                s0 += x[i].x * c.x + x[i].y * c.y + x[i].z * c.z + x[i].w * c.w;
            }
            float sc = s0 - CChalf[k];
            if (sc > best) { best = sc; bestk = k; }
        }
        y[row] = bestk;
        atomicAdd(&count[bestk], 1);
        mind = sqrtf(fmaxf(xx - 2.f * best, 0.f) * (1.0f / 64.0f));
    }
    float s = mind;
#pragma unroll
    for (int off = 32; off > 0; off >>= 1) s += __shfl_xor(s, off);
    __shared__ float wsum[4];
    int w = threadIdx.x >> 6;
    if ((threadIdx.x & 63) == 0) wsum[w] = s;
    __syncthreads();
    if (threadIdx.x == 0)
        atomicAdd(inertia_ws, wsum[0] + wsum[1] + wsum[2] + wsum[3]);
}

__global__ __launch_bounds__(256) void accum_atomic_kernel(
        const float* __restrict__ X, const float* __restrict__ W,
        const int* __restrict__ y, float* __restrict__ out, int n) {
    int row = blockIdx.x * blockDim.x + threadIdx.x;
    if (row >= n) return;
    int k = y[row];
    const float4* xp = (const float4*)(X + (size_t)row * D_DIM);
    const float4* wp = (const float4*)(W + (size_t)row * D_DIM);
    float* xw = out + (size_t)k * D_DIM;
    float* wsv = out + (size_t)(K_CLUS + k) * D_DIM;
#pragma unroll
    for (int i = 0; i < 16; ++i) {
        float4 x = xp[i];
        float4 wq = wp[i];
        atomicAdd(xw + 4 * i + 0, x.x * wq.x);
        atomicAdd(xw + 4 * i + 1, x.y * wq.y);
        atomicAdd(xw + 4 * i + 2, x.z * wq.z);
        atomicAdd(xw + 4 * i + 3, x.w * wq.w);
        atomicAdd(wsv + 4 * i + 0, wq.x);
        atomicAdd(wsv + 4 * i + 1, wq.y);
        atomicAdd(wsv + 4 * i + 2, wq.z);
        atomicAdd(wsv + 4 * i + 3, wq.w);
    }
}

extern "C" void kernel_launch(void* const* d_in, const int* in_sizes, int n_in,
                              void* d_out, int out_size, void* d_ws, size_t ws_size,
                              hipStream_t stream) {
    const float* X = (const float*)d_in[0];
    const float* C = (const float*)d_in[1];
    const float* W = (const float*)d_in[2];
    float* out = (float*)d_out;
    int n = in_sizes[0] / D_DIM;        // 500000
    int k_total = in_sizes[1] / D_DIM;  // 512

    char* ws = (char*)d_ws;
    int*            count   = (int*)ws;                      // 2 KB
    float*          inertia = (float*)(ws + 2048);
    float*          cchalf  = (float*)(ws + 2560);           // 2 KB
    int*            offset  = (int*)(ws + 8192);             // 2 KB
    unsigned short* Cb      = (unsigned short*)(ws + 12288); // 64 KB bf16 C
    int*            yv      = (int*)(ws + 81920);
    int*            rank    = (int*)(ws + 81920 + (size_t)n * 4);
    int*            sorted  = (int*)(ws + 81920 + (size_t)n * 8);
    size_t needed = 81920 + (size_t)n * 12;

    int nblk = (n + 255) / 256;

    hipMemsetAsync(ws, 0, 4096, stream);                       // count + inertia
    hipMemsetAsync(d_out, 0, (size_t)out_size * sizeof(float), stream);
    cc_kernel<<<(k_total + 255) / 256, 256, 0, stream>>>(C, cchalf, Cb, k_total);

    if (ws_size >= needed) {
        int ntiles = (n + RPT - 1) / RPT;
        int agrid = ntiles < 512 ? ntiles : 512;   // 2 blocks/CU, persistent
        assign_mfma<<<agrid, 512, 0, stream>>>(X, Cb, cchalf, yv, rank, count, inertia, n, ntiles);
        prefix_kernel<<<1, K_CLUS, 0, stream>>>(count, offset);
        scatter_kernel<<<nblk, 256, 0, stream>>>(yv, rank, offset, sorted, n);
        cluster_accum_seg<<<k_total * SEG, 256, 0, stream>>>(X, W, sorted, offset, count, out);
        finalize_kernel<<<1, D_DIM, 0, stream>>>(inertia, out);
    } else {
        assign_scalar<<<nblk, 256, 0, stream>>>(X, C, cchalf, yv, count, inertia, n);
        accum_atomic_kernel<<<nblk, 256, 0, stream>>>(X, W, yv, out, n);
        finalize_kernel<<<1, D_DIM, 0, stream>>>(inertia, out);
    }
}

// Round 7
// 161.108 us; speedup vs baseline: 4.3448x; 2.3996x over previous
//
#include <hip/hip_runtime.h>
#include <hip/hip_bf16.h>

// N=500000, D=64, K=512 (fp32 in/out).
// out rows: [0,K)=xw_sum, [K,2K)=w_sum, row 2K = inertia broadcast to 64 cols.

#define D_DIM 64
#define K_CLUS 512
#define SEG 16
#define SEG_SHIFT 4
#define RPT 64            // X rows per tile in assign
#define AGRID_MAX 1024    // assign grid (4 blocks/CU)

typedef __attribute__((ext_vector_type(8))) short short8;
typedef __attribute__((ext_vector_type(4))) float f32x4;

__device__ inline float dot4sq(float4 a) {
    return a.x * a.x + a.y * a.y + a.z * a.z + a.w * a.w;
}
__device__ inline unsigned short bfb(float f) {   // fp32 -> bf16 bits, RNE
    unsigned int u = __float_as_uint(f);
    return (unsigned short)((u + 0x7FFFu + ((u >> 16) & 1u)) >> 16);
}
// fast pack via v_cvt_pk_bf16_f32 (compiler-generated, RNE)
__device__ inline short8 pack8f(float4 a, float4 b) {
    union { short8 s; __hip_bfloat162 q[4]; } r;
    r.q[0] = __float22bfloat162_rn(make_float2(a.x, a.y));
    r.q[1] = __float22bfloat162_rn(make_float2(a.z, a.w));
    r.q[2] = __float22bfloat162_rn(make_float2(b.x, b.y));
    r.q[3] = __float22bfloat162_rn(make_float2(b.z, b.w));
    return r.s;
}
__device__ inline float4 shfl_xor4(float4 v, int m) {
    float4 r;
    r.x = __shfl_xor(v.x, m); r.y = __shfl_xor(v.y, m);
    r.z = __shfl_xor(v.z, m); r.w = __shfl_xor(v.w, m);
    return r;
}

// ---------------- Kernel 1: half-norms + bf16 pack of centroids ----------------
__global__ void cc_kernel(const float* __restrict__ C, float* __restrict__ CChalf,
                          unsigned short* __restrict__ Cb, int k_total) {
    int k = blockIdx.x * blockDim.x + threadIdx.x;
    if (k >= k_total) return;
    const float4* cp = (const float4*)(C + (size_t)k * D_DIM);
    unsigned short* ob = Cb + (size_t)k * D_DIM;
    float s = 0.f;
#pragma unroll
    for (int i = 0; i < 16; ++i) {
        float4 c = cp[i];
        s += dot4sq(c);
        ob[4 * i + 0] = bfb(c.x); ob[4 * i + 1] = bfb(c.y);
        ob[4 * i + 2] = bfb(c.z); ob[4 * i + 3] = bfb(c.w);
    }
    CChalf[k] = 0.5f * s;
}

// ---------------- Kernel 2: MFMA assignment, C-in-registers ----------------
// Wave w owns clusters [w*64,(w+1)*64) as MFMA A-frags in registers; X tiles
// (64 rows bf16, XOR-swizzled) staged in LDS as B-frags. -0.5||c||^2 folded
// into acc init. Per-row rank via LDS histogram (no per-row global atomics);
// per-block base flushed once at the end into baseTab.
__global__ __launch_bounds__(512, 4) void assign_mfma(
        const float* __restrict__ X, const unsigned short* __restrict__ Cb,
        const float* __restrict__ CChalf, int* __restrict__ y,
        int* __restrict__ lrank, int* __restrict__ baseTab,
        int* __restrict__ count, float* __restrict__ inertia_ws,
        int n, int ntiles) {
    __shared__ __align__(16) char xb_lds[RPT * 128];        // 8 KB bf16, swizzled
    __shared__ __align__(16) unsigned int partial[RPT][8];  // 2 KB keys
    __shared__ float xs_lds[2][RPT];                        // ||x||^2, dbuf
    __shared__ int lhist[K_CLUS];                           // 2 KB local histogram

    int tid = threadIdx.x;
    lhist[tid] = 0;                                         // 512 threads == K_CLUS

    int lane = tid & 63, wid = tid >> 6;
    int c15 = lane & 15, g = lane >> 4;
    int wbase = wid * 64;

    // wave's 64 clusters -> registers (A-frags) + negated half-norms
    short8 cf0[4], cf1[4];
    float ncch[16];
#pragma unroll
    for (int ct = 0; ct < 4; ++ct) {
        const char* cp = (const char*)(Cb + (size_t)(wbase + ct * 16 + c15) * D_DIM);
        cf0[ct] = *(const short8*)(cp + (g << 4));          // k = 8g..8g+7
        cf1[ct] = *(const short8*)(cp + 64 + (g << 4));     // k = 32+8g..
#pragma unroll
        for (int r2 = 0; r2 < 4; ++r2)
            ncch[ct * 4 + r2] = -CChalf[wbase + ct * 16 + (g << 2) + r2];
    }

    // stage mapping: thread -> one 16B bf16 chunk of the 8KB tile
    int srow = tid >> 3;             // 0..63
    int sb = (tid & 7) << 4;         // bf16 byte offset
    int sf = (tid & 7) << 3;         // fp32 elem offset
    unsigned swz = ((unsigned)(srow & 7)) << 4;

    float4 s0 = {0,0,0,0}, s1 = {0,0,0,0};
    int tile = blockIdx.x;
    if (tile < ntiles) {
        int grow = min(tile * RPT + srow, n - 1);
        const float4* xp = (const float4*)(X + (size_t)grow * D_DIM + sf);
        s0 = xp[0]; s1 = xp[1];
    }
    float iner = 0.f;
    int it = 0;

    for (; tile < ntiles; tile += gridDim.x, ++it) {
        int par = it & 1;
        // ---- stage tile -> LDS (swizzled) + ||x||^2 partials ----
        *(short8*)(xb_lds + (srow << 7) + (sb ^ swz)) = pack8f(s0, s1);
        float ps = dot4sq(s0) + dot4sq(s1);
        ps += __shfl_xor(ps, 1); ps += __shfl_xor(ps, 2); ps += __shfl_xor(ps, 4);
        if ((tid & 7) == 0) xs_lds[par][srow] = ps;
        __syncthreads();                                   // stage visible

        // issue next tile's loads (latency hides under sweep)
        int ntile = tile + gridDim.x;
        if (ntile < ntiles) {
            int grow = min(ntile * RPT + srow, n - 1);
            const float4* xp = (const float4*)(X + (size_t)grow * D_DIM + sf);
            s0 = xp[0]; s1 = xp[1];
        }

        // ---- sweep: 4 row-subtiles x wave's 64 clusters ----
#pragma unroll
        for (int s = 0; s < 4; ++s) {
            int arow = s * 16 + c15;                       // x-row (B col)
            const char* ab = xb_lds + (arow << 7);
            unsigned asw = ((unsigned)(c15 & 7)) << 4;
            short8 xa = *(const short8*)(ab + ((g << 4) ^ asw));
            short8 xbv = *(const short8*)(ab + ((64 + (g << 4)) ^ asw));

            float best = -3.4e38f;
            int bpos = 0;
#pragma unroll
            for (int ct = 0; ct < 4; ++ct) {
                f32x4 accA = {ncch[ct * 4 + 0], ncch[ct * 4 + 1],
                              ncch[ct * 4 + 2], ncch[ct * 4 + 3]};
                f32x4 accB = {0.f, 0.f, 0.f, 0.f};
                accA = __builtin_amdgcn_mfma_f32_16x16x32_bf16(cf0[ct], xa, accA, 0, 0, 0);
                accB = __builtin_amdgcn_mfma_f32_16x16x32_bf16(cf1[ct], xbv, accB, 0, 0, 0);
                float sc0 = accA[0] + accB[0];
                float sc1 = accA[1] + accB[1];
                float sc2 = accA[2] + accB[2];
                float sc3 = accA[3] + accB[3];
                // tree-compare, ties -> lower index
                bool b01 = sc1 > sc0;  float v01 = b01 ? sc1 : sc0;  int p01 = b01 ? 1 : 0;
                bool b23 = sc3 > sc2;  float v23 = b23 ? sc3 : sc2;  int p23 = b23 ? 3 : 2;
                bool bq  = v23 > v01;  float vq  = bq ? v23 : v01;   int pq  = bq ? p23 : p01;
                if (vq > best) { best = vq; bpos = (ct << 2) + pq; }   // ct ascending = k ascending
            }
            // pack (score, k) into monotone key; reduce over g (lanes ^16,^32)
            int kg = wbase + ((bpos >> 2) << 4) + (g << 2) + (bpos & 3);
            unsigned u = __float_as_uint(best);
            unsigned mono = u ^ ((u & 0x80000000u) ? 0xFFFFFFFFu : 0x80000000u);
            unsigned key = (mono & 0xFFFFFE00u) | ((unsigned)kg ^ 0x1FFu);
            unsigned o = (unsigned)__shfl_xor((int)key, 16); key = key > o ? key : o;
            o = (unsigned)__shfl_xor((int)key, 32); key = key > o ? key : o;
            if (g == 0) partial[s * 16 + c15][wid] = key;
        }
        __syncthreads();                                   // partials visible

        // ---- merge: 64 threads, one row each; rank via LDS atomic ----
        if (tid < RPT) {
            int grow = tile * RPT + tid;
            if (grow < n) {
                const uint4* pp = (const uint4*)&partial[tid][0];
                uint4 p0 = pp[0], p1 = pp[1];
                unsigned key = p0.x;
                key = key > p0.y ? key : p0.y;
                key = key > p0.z ? key : p0.z;
                key = key > p0.w ? key : p0.w;
                key = key > p1.x ? key : p1.x;
                key = key > p1.y ? key : p1.y;
                key = key > p1.z ? key : p1.z;
                key = key > p1.w ? key : p1.w;
                int kg = (int)((key & 0x1FFu) ^ 0x1FFu);
                unsigned m2 = (key & 0xFFFFFE00u) | 0x100u;    // midpoint restore
                unsigned ub = (m2 & 0x80000000u) ? (m2 ^ 0x80000000u) : ~m2;
                float sbest = __uint_as_float(ub);
                float xx = xs_lds[par][tid];
                y[grow] = kg;
                lrank[grow] = atomicAdd(&lhist[kg], 1);        // LDS atomic, fast
                iner += sqrtf(fmaxf(xx - 2.f * sbest, 0.f) * (1.0f / 64.0f));
            }
        }
    }

    // ---- flush local histogram -> global bases (one wave-atomic per wave) ----
    __syncthreads();
    int b = atomicAdd(count + tid, lhist[tid]);
    baseTab[blockIdx.x * K_CLUS + tid] = b;

    // inertia: only wave 0 accumulated
    if (wid == 0) {
#pragma unroll
        for (int off = 1; off < 64; off <<= 1) iner += __shfl_xor(iner, off);
        if (lane == 0) atomicAdd(inertia_ws, iner);
    }
}

// ---------------- Kernel 3: exclusive prefix sum over 512 counts ----------------
__global__ __launch_bounds__(K_CLUS) void prefix_kernel(
        const int* __restrict__ count, int* __restrict__ offset) {
    __shared__ int tmp[K_CLUS];
    int t = threadIdx.x;
    tmp[t] = count[t];
    __syncthreads();
    for (int s = 1; s < K_CLUS; s <<= 1) {
        int v = (t >= s) ? tmp[t - s] : 0;
        __syncthreads();
        tmp[t] += v;
        __syncthreads();
    }
    offset[t] = tmp[t] - count[t];
}

// ---------------- Kernel 4: scatter rows into cluster-sorted order ----------------
__global__ __launch_bounds__(256) void scatter_kernel(
        const int* __restrict__ y, const int* __restrict__ lrank,
        const int* __restrict__ offset, const int* __restrict__ baseTab,
        int* __restrict__ sorted, int n, int agrid) {
    int row = blockIdx.x * blockDim.x + threadIdx.x;
    if (row >= n) return;
    int k = y[row];
    int blk = (row >> 6) % agrid;     // RPT=64 rows per tile
    sorted[offset[k] + baseTab[blk * K_CLUS + k] + lrank[row]] = row;
}

// ---------------- Kernel 5: segmented per-cluster accumulation ----------------
__global__ __launch_bounds__(256) void cluster_accum_seg(
        const float* __restrict__ X, const float* __restrict__ W,
        const int* __restrict__ sorted, const int* __restrict__ offset,
        const int* __restrict__ count, float* __restrict__ out) {
    int bid = blockIdx.x;
    int k = bid >> SEG_SHIFT;
    int seg = bid & (SEG - 1);
    int cnt = count[k];
    int chunk = (cnt + SEG - 1) >> SEG_SHIFT;
    int lo = seg * chunk;
    int hi = min(cnt, lo + chunk);
    int start = offset[k];
    int lane = threadIdx.x & 63, w = threadIdx.x >> 6;
    int rsub = lane >> 4, col4 = lane & 15;
    const float4* X4 = (const float4*)X;
    const float4* W4 = (const float4*)W;

    float4 ax = {0.f, 0.f, 0.f, 0.f}, aw = {0.f, 0.f, 0.f, 0.f};
    for (int base = lo + w * 4; base < hi; base += 16) {
        int ii = base + rsub;
        if (ii < hi) {
            int row = sorted[start + ii];
            float4 xv = X4[(size_t)row * 16 + col4];
            float4 wv = W4[(size_t)row * 16 + col4];
            ax.x = fmaf(xv.x, wv.x, ax.x); ax.y = fmaf(xv.y, wv.y, ax.y);
            ax.z = fmaf(xv.z, wv.z, ax.z); ax.w = fmaf(xv.w, wv.w, ax.w);
            aw.x += wv.x; aw.y += wv.y; aw.z += wv.z; aw.w += wv.w;
        }
    }
    float4 t;
    t = shfl_xor4(ax, 16); ax.x += t.x; ax.y += t.y; ax.z += t.z; ax.w += t.w;
    t = shfl_xor4(ax, 32); ax.x += t.x; ax.y += t.y; ax.z += t.z; ax.w += t.w;
    t = shfl_xor4(aw, 16); aw.x += t.x; aw.y += t.y; aw.z += t.z; aw.w += t.w;
    t = shfl_xor4(aw, 32); aw.x += t.x; aw.y += t.y; aw.z += t.z; aw.w += t.w;

    __shared__ float4 sx4[4][16];
    __shared__ float4 sw4[4][16];
    if (lane < 16) { sx4[w][lane] = ax; sw4[w][lane] = aw; }
    __syncthreads();
    if (threadIdx.x < 16) {
        int c = threadIdx.x;
        float4 tx = {0.f, 0.f, 0.f, 0.f}, tw = {0.f, 0.f, 0.f, 0.f};
#pragma unroll
        for (int j = 0; j < 4; ++j) {
            float4 a = sx4[j][c], b = sw4[j][c];
            tx.x += a.x; tx.y += a.y; tx.z += a.z; tx.w += a.w;
            tw.x += b.x; tw.y += b.y; tw.z += b.z; tw.w += b.w;
        }
        float* xw = out + (size_t)k * D_DIM + c * 4;
        float* wp = out + (size_t)(K_CLUS + k) * D_DIM + c * 4;
        atomicAdd(xw + 0, tx.x); atomicAdd(xw + 1, tx.y);
        atomicAdd(xw + 2, tx.z); atomicAdd(xw + 3, tx.w);
        atomicAdd(wp + 0, tw.x); atomicAdd(wp + 1, tw.y);
        atomicAdd(wp + 2, tw.z); atomicAdd(wp + 3, tw.w);
    }
}

// ---------------- Kernel 6: broadcast inertia ----------------
__global__ void finalize_kernel(const float* __restrict__ inertia_ws, float* __restrict__ out) {
    out[(size_t)(2 * K_CLUS) * D_DIM + threadIdx.x] = *inertia_ws;
}

// ---------------- Fallback path (ws too small) ----------------
__global__ __launch_bounds__(256) void assign_scalar(
        const float* __restrict__ X, const float* __restrict__ C,
        const float* __restrict__ CChalf, int* __restrict__ y,
        int* __restrict__ count, float* __restrict__ inertia_ws, int n) {
    int row = blockIdx.x * blockDim.x + threadIdx.x;
    float mind = 0.f;
    if (row < n) {
        float4 x[16];
        const float4* xp = (const float4*)(X + (size_t)row * D_DIM);
#pragma unroll
        for (int i = 0; i < 16; ++i) x[i] = xp[i];
        float xx = 0.f;
#pragma unroll
        for (int i = 0; i < 16; ++i) xx += dot4sq(x[i]);
        float best = -3.4e38f;
        int bestk = 0;
        for (int k = 0; k < K_CLUS; ++k) {
            const float4* cp = (const float4*)(C + (size_t)k * D_DIM);
            float s0 = 0.f;
#pragma unroll
            for (int i = 0; i < 16; ++i) {
                float4 c = cp[i];
                s0 += x[i].x * c.x + x[i].y * c.y + x[i].z * c.z + x[i].w * c.w;
            }
            float sc = s0 - CChalf[k];
            if (sc > best) { best = sc; bestk = k; }
        }
        y[row] = bestk;
        atomicAdd(&count[bestk], 1);
        mind = sqrtf(fmaxf(xx - 2.f * best, 0.f) * (1.0f / 64.0f));
    }
    float s = mind;
#pragma unroll
    for (int off = 32; off > 0; off >>= 1) s += __shfl_xor(s, off);
    __shared__ float wsum[4];
    int w = threadIdx.x >> 6;
    if ((threadIdx.x & 63) == 0) wsum[w] = s;
    __syncthreads();
    if (threadIdx.x == 0)
        atomicAdd(inertia_ws, wsum[0] + wsum[1] + wsum[2] + wsum[3]);
}

__global__ __launch_bounds__(256) void accum_atomic_kernel(
        const float* __restrict__ X, const float* __restrict__ W,
        const int* __restrict__ y, float* __restrict__ out, int n) {
    int row = blockIdx.x * blockDim.x + threadIdx.x;
    if (row >= n) return;
    int k = y[row];
    const float4* xp = (const float4*)(X + (size_t)row * D_DIM);
    const float4* wp = (const float4*)(W + (size_t)row * D_DIM);
    float* xw = out + (size_t)k * D_DIM;
    float* wsv = out + (size_t)(K_CLUS + k) * D_DIM;
#pragma unroll
    for (int i = 0; i < 16; ++i) {
        float4 x = xp[i];
        float4 wq = wp[i];
        atomicAdd(xw + 4 * i + 0, x.x * wq.x);
        atomicAdd(xw + 4 * i + 1, x.y * wq.y);
        atomicAdd(xw + 4 * i + 2, x.z * wq.z);
        atomicAdd(xw + 4 * i + 3, x.w * wq.w);
        atomicAdd(wsv + 4 * i + 0, wq.x);
        atomicAdd(wsv + 4 * i + 1, wq.y);
        atomicAdd(wsv + 4 * i + 2, wq.z);
        atomicAdd(wsv + 4 * i + 3, wq.w);
    }
}

extern "C" void kernel_launch(void* const* d_in, const int* in_sizes, int n_in,
                              void* d_out, int out_size, void* d_ws, size_t ws_size,
                              hipStream_t stream) {
    const float* X = (const float*)d_in[0];
    const float* C = (const float*)d_in[1];
    const float* W = (const float*)d_in[2];
    float* out = (float*)d_out;
    int n = in_sizes[0] / D_DIM;        // 500000
    int k_total = in_sizes[1] / D_DIM;  // 512

    char* ws = (char*)d_ws;
    int*            count   = (int*)ws;                      // 2 KB
    float*          inertia = (float*)(ws + 2048);
    float*          cchalf  = (float*)(ws + 2560);           // 2 KB
    int*            offset  = (int*)(ws + 8192);             // 2 KB
    unsigned short* Cb      = (unsigned short*)(ws + 12288); // 64 KB bf16 C
    int*            yv      = (int*)(ws + 81920);
    int*            lrank   = (int*)(ws + 81920 + (size_t)n * 4);
    int*            sorted  = (int*)(ws + 81920 + (size_t)n * 8);
    int*            baseTab = (int*)(ws + 81920 + (size_t)n * 12);
    size_t needed = 81920 + (size_t)n * 12 + (size_t)AGRID_MAX * K_CLUS * 4;

    int nblk = (n + 255) / 256;

    hipMemsetAsync(ws, 0, 4096, stream);                       // count + inertia
    hipMemsetAsync(d_out, 0, (size_t)out_size * sizeof(float), stream);
    cc_kernel<<<(k_total + 255) / 256, 256, 0, stream>>>(C, cchalf, Cb, k_total);

    if (ws_size >= needed) {
        int ntiles = (n + RPT - 1) / RPT;
        int agrid = ntiles < AGRID_MAX ? ntiles : AGRID_MAX;   // 4 blocks/CU
        assign_mfma<<<agrid, 512, 0, stream>>>(X, Cb, cchalf, yv, lrank, baseTab,
                                               count, inertia, n, ntiles);
        prefix_kernel<<<1, K_CLUS, 0, stream>>>(count, offset);
        scatter_kernel<<<nblk, 256, 0, stream>>>(yv, lrank, offset, baseTab, sorted, n, agrid);
        cluster_accum_seg<<<k_total * SEG, 256, 0, stream>>>(X, W, sorted, offset, count, out);
        finalize_kernel<<<1, D_DIM, 0, stream>>>(inertia, out);
    } else {
        assign_scalar<<<nblk, 256, 0, stream>>>(X, C, cchalf, yv, count, inertia, n);
        accum_atomic_kernel<<<nblk, 256, 0, stream>>>(X, W, yv, out, n);
        finalize_kernel<<<1, D_DIM, 0, stream>>>(inertia, out);
    }
}